// Round 2
// baseline (861.177 us; speedup 1.0000x reference)
//
#include <hip/hip_runtime.h>
#include <hip/hip_bf16.h>
#include <stdint.h>

// Problem constants (fixed by reference)
#define DIMN    2048
#define HIDDEN  2048
#define NHEADS  4
#define HDIM    512
#define BATCH   4
#define SEQ     2048
#define NTOK    (BATCH*SEQ)      // 8192 tokens
#define G4      (4*HIDDEN)       // 8192 gate width
#define EPSV    1e-6f
#define CHUNK   128
#define NCHUNK  (SEQ/CHUNK)      // 16

typedef short short8 __attribute__((ext_vector_type(8)));
typedef float floatx4 __attribute__((ext_vector_type(4)));

union BV8 { uint4 u; __hip_bfloat16 h[8]; unsigned short s[8]; };

__device__ __forceinline__ float fast_sigmoid(float x) {
    return 1.0f / (1.0f + __expf(-x));
}
__device__ __forceinline__ float fast_tanh(float x) {
    return 1.0f - 2.0f / (__expf(2.0f * x) + 1.0f);
}
__device__ __forceinline__ float b2f(unsigned short u) {
    union { unsigned int ui; float f; } v; v.ui = ((unsigned int)u) << 16; return v.f;
}

// async global->LDS, 16B per lane; LDS dest = wave-uniform base + lane*16
__device__ __forceinline__ void gld_lds16(const void* gp, void* lp) {
    __builtin_amdgcn_global_load_lds(
        (const __attribute__((address_space(1))) void*)gp,
        (__attribute__((address_space(3))) void*)lp, 16, 0, 0);
}

// ---------------------------------------------------------------------------
// f32 -> bf16 cast, 8 elems/thread
// ---------------------------------------------------------------------------
__global__ __launch_bounds__(256) void cast_f32_bf16(
    const float* __restrict__ in, __hip_bfloat16* __restrict__ out, int n8)
{
    int i = blockIdx.x * 256 + threadIdx.x;
    if (i >= n8) return;
    const float4* p = (const float4*)(in + (size_t)i * 8);
    float4 a = p[0], b = p[1];
    BV8 v;
    v.h[0] = __float2bfloat16(a.x); v.h[1] = __float2bfloat16(a.y);
    v.h[2] = __float2bfloat16(a.z); v.h[3] = __float2bfloat16(a.w);
    v.h[4] = __float2bfloat16(b.x); v.h[5] = __float2bfloat16(b.y);
    v.h[6] = __float2bfloat16(b.z); v.h[7] = __float2bfloat16(b.w);
    *(uint4*)(out + (size_t)i * 8) = v.u;
}

// ---------------------------------------------------------------------------
// GEMM: C[M][N] = A[M][K] @ Bt[N][K]^T   (bf16 in, fp32 acc)
// 256x256 tile, BK=64, 512 threads = 8 waves (2M x 4N), each wave 128x64.
// 4 phases/K-tile, ONE barrier per phase, NO intra-phase lgkmcnt pin:
// the backend's counted lgkmcnt lets each phase's MFMA cluster start as soon
// as its first operands return, hiding the LDS service tail under MFMA
// (round-1 evidence: manual lgkmcnt(0)+sched_barrier per phase serialized
// LDS+MFMA -> 833 TF, MfmaUtil 36%). sched_barrier(0) only AFTER each
// s_barrier pins loads below barriers (cross-wave staging safety).
//
// Balanced read stream 8/4/8/4 per phase; B-q0 of tile t+1 is prefetched in
// tile t's phase 3 into a ping-ponged register set (b0a/b0b, loop unrolled
// x2 so all register indexing is static).
//
// Region-hazard ledger (stage S writes region R: need all reads of R
// complete (consumed by an in-phase MFMA => done at that phase-end barrier,
// lgkm completes in-order) >=1 barrier before S issues):
//   ph0 stage A(t+1,q1) -> A[b^1]q1: read as av in (t-1)ph2, done (t-1)ph2-end.
//   ph1 stage A(t+2,q0) -> A[b]q0:   read as av in ph0, done ph0-end.
//   ph2 stage B(t+2,q0) -> B[b]q0:   read as b0 in (t-1)ph3, done (t-1)ph3-end
//                                    (consumed by ph0 MFMA of tile t... reads
//                                    issued (t-1)ph3, consumed t ph0 -> done
//                                    by t ph0-end barrier; ph2 is 2 barriers later).
//   ph3 stage B(t+2,q1) -> B[b]q1:   read as b1 in ph1, done ph1-end.
// Staging-completion (vmcnt(N)+barrier => all waves' loads older than the
// newest N/2 chunks are visible): per-tile vmcnt(4) at ph2-end leaves only
// {A(t+2,q0), B(t+2,q0)} outstanding =>
//   ph3 reads B(t+1,q0) [staged (t-1)ph2]  - covered by t ph2-end vmcnt(4).
//   (t+1)ph0 reads A(t+1,q0) [(t-1)ph1]    - covered (older).
//   (t+1)ph1 reads B(t+1,q1) [(t-1)ph3]    - covered (older).
//   (t+1)ph2 reads A(t+1,q1) [t ph0]       - covered by t ph2-end vmcnt(4)?
//     no: A(t+1,q1) is 3rd-newest at that point -> covered (vmcnt(4)=2 chunks).
// Tail: t==NT-2 uses vmcnt(0) (one-time full drain), t==NT-1 none.
// Swizzle: source-chunk XOR (LDS[row][c]=G[row][c^(row&7)], 16B granules) --
// measured SQ_LDS_BANK_CONFLICT == 0 with the matching read-side XOR.
// EPILOGUE: 0 = bf16 store; 1 = bias+gate activations -> bf16; 2 = f32 store
// ASRC: 0 = contiguous rows; 1 = head-gather (row,k) -> Ag[row*lda +
//       (k>>9)*2048 + (k&511)]  (BK=64 chunk never crosses a 512 block)
// ---------------------------------------------------------------------------
template <int EPILOGUE, int ASRC>
__global__ __launch_bounds__(512, 2) void gemm256(
    const __hip_bfloat16* __restrict__ A,
    const __hip_bfloat16* __restrict__ Bt,
    void* __restrict__ Cout,
    const float* __restrict__ bias,
    int M, int N, int K, int lda)
{
    __shared__ __align__(16) short sA[2][256 * 64];   // 64 KiB
    __shared__ __align__(16) short sB[2][256 * 64];   // 64 KiB

    const int tid  = threadIdx.x;
    const int wave = tid >> 6, lane = tid & 63;
    const int wm = wave >> 2, wn = wave & 3;          // 2 x 4 wave grid
    const int quad = lane >> 4, lr = lane & 15;
    const int r8  = lane >> 3;                        // row within 8-row slab
    const int gcs = ((lane & 7) ^ r8) * 8;            // swizzled src chunk (shorts)
    const int rl7 = lr & 7;

    // bijective XCD swizzle (all launch shapes have nwg % 8 == 0)
    const int gx   = gridDim.x;
    const int nwg  = gx * gridDim.y;
    const int orig = blockIdx.y * gx + blockIdx.x;
    const int wg   = (orig & 7) * (nwg >> 3) + (orig >> 3);
    const int bm = wg / gx, bn = wg % gx;

    const short* Ag = (const short*)A + (size_t)(bm * 256) * lda;
    const short* Bg = (const short*)Bt + (size_t)(bn * 256) * K;

    floatx4 acc[8][4];
#pragma unroll
    for (int i = 0; i < 8; ++i)
#pragma unroll
        for (int j = 0; j < 4; ++j) acc[i][j] = (floatx4)0.0f;

    const int NT = K >> 6;

    auto stageA = [&](int kt, int qm) {
        const int kb = kt << 6;
        size_t acol;
        if (ASRC == 0) acol = (size_t)(kb + gcs);
        else           acol = (size_t)(((kb >> 9) << 11) + (kb & 511) + gcs);
        short* dst = &sA[kt & 1][0];
#pragma unroll
        for (int e = 0; e < 2; ++e) {
            const int base = qm * 128 + e * 64 + wave * 8;   // wave-uniform
            const int row  = base + r8;
            const int grow = ((row >> 6) & 1) * 128 + qm * 64 + (row & 63);
            gld_lds16(Ag + (size_t)grow * lda + acol, dst + base * 64);
        }
    };
    auto stageB = [&](int kt, int qn) {
        const int kb = kt << 6;
        short* dst = &sB[kt & 1][0];
#pragma unroll
        for (int e = 0; e < 2; ++e) {
            const int base = qn * 128 + e * 64 + wave * 8;   // wave-uniform
            const int row  = base + r8;
            const int grow = ((row >> 5) & 3) * 64 + qn * 32 + (row & 31);
            gld_lds16(Bg + (size_t)grow * K + kb + gcs, dst + base * 64);
        }
    };

    // prologue: tile0 c0..c3, tile1 {A-q0, B-q0, B-q1} (7 chunks, 14 loads);
    // vmcnt(6) -> tile0 fully resident (newest 3 chunks may be in flight).
    stageA(0, 0); stageB(0, 0); stageB(0, 1); stageA(0, 1);
    stageA(1, 0); stageB(1, 0); stageB(1, 1);
    asm volatile("s_waitcnt vmcnt(6)" ::: "memory");
    __builtin_amdgcn_s_barrier();
    __builtin_amdgcn_sched_barrier(0);

    short8 av[4][2], b1[2][2], b0a[2][2], b0b[2][2];

    // preload b0 for tile 0 from B[0] q0
#pragma unroll
    for (int kc = 0; kc < 2; ++kc) {
        const int co = (((kc * 4 + quad) ^ rl7) << 3);
#pragma unroll
        for (int j = 0; j < 2; ++j)
            b0a[j][kc] = *(const short8*)&sB[0][(wn * 32 + j * 16 + lr) * 64 + co];
    }

    auto tile_body = [&](int t_, short8 (&BCUR)[2][2], short8 (&BNEXT)[2][2]) {
        const short* lA = &sA[t_ & 1][0];
        const short* lB = &sB[t_ & 1][0];

        // ---- phase 0: read A-q0 (8); stage A(t+1,q1); MFMA Q00 (av x BCUR)
#pragma unroll
        for (int kc = 0; kc < 2; ++kc) {
            const int co = (((kc * 4 + quad) ^ rl7) << 3);
#pragma unroll
            for (int m = 0; m < 4; ++m)
                av[m][kc] = *(const short8*)&lA[(wm * 64 + m * 16 + lr) * 64 + co];
        }
        if (t_ + 1 < NT) stageA(t_ + 1, 1);
        __builtin_amdgcn_s_setprio(1);
#pragma unroll
        for (int m = 0; m < 4; ++m)
#pragma unroll
            for (int j = 0; j < 2; ++j)
#pragma unroll
                for (int kc = 0; kc < 2; ++kc)
                    acc[m][j] = __builtin_amdgcn_mfma_f32_16x16x32_bf16(
                        av[m][kc], BCUR[j][kc], acc[m][j], 0, 0, 0);
        __builtin_amdgcn_s_setprio(0);
        __builtin_amdgcn_s_barrier();
        __builtin_amdgcn_sched_barrier(0);

        // ---- phase 1: read B-q1 (4); stage A(t+2,q0); MFMA Q01 (av x b1)
#pragma unroll
        for (int kc = 0; kc < 2; ++kc) {
            const int co = (((kc * 4 + quad) ^ rl7) << 3);
#pragma unroll
            for (int j = 0; j < 2; ++j)
                b1[j][kc] = *(const short8*)&lB[(128 + wn * 32 + j * 16 + lr) * 64 + co];
        }
        if (t_ + 2 < NT) stageA(t_ + 2, 0);
        __builtin_amdgcn_s_setprio(1);
#pragma unroll
        for (int m = 0; m < 4; ++m)
#pragma unroll
            for (int j = 0; j < 2; ++j)
#pragma unroll
                for (int kc = 0; kc < 2; ++kc)
                    acc[m][2 + j] = __builtin_amdgcn_mfma_f32_16x16x32_bf16(
                        av[m][kc], b1[j][kc], acc[m][2 + j], 0, 0, 0);
        __builtin_amdgcn_s_setprio(0);
        __builtin_amdgcn_s_barrier();
        __builtin_amdgcn_sched_barrier(0);

        // ---- phase 2: read A-q1 (8, overwrite av); stage B(t+2,q0);
        //               MFMA Q11 (av x b1); counted vmcnt; barrier
#pragma unroll
        for (int kc = 0; kc < 2; ++kc) {
            const int co = (((kc * 4 + quad) ^ rl7) << 3);
#pragma unroll
            for (int m = 0; m < 4; ++m)
                av[m][kc] = *(const short8*)&lA[(128 + wm * 64 + m * 16 + lr) * 64 + co];
        }
        if (t_ + 2 < NT) stageB(t_ + 2, 0);
        __builtin_amdgcn_s_setprio(1);
#pragma unroll
        for (int m = 0; m < 4; ++m)
#pragma unroll
            for (int j = 0; j < 2; ++j)
#pragma unroll
                for (int kc = 0; kc < 2; ++kc)
                    acc[4 + m][2 + j] = __builtin_amdgcn_mfma_f32_16x16x32_bf16(
                        av[m][kc], b1[j][kc], acc[4 + m][2 + j], 0, 0, 0);
        __builtin_amdgcn_s_setprio(0);
        if (t_ < NT - 2)       asm volatile("s_waitcnt vmcnt(4)" ::: "memory");
        else if (t_ == NT - 2) asm volatile("s_waitcnt vmcnt(0)" ::: "memory");
        __builtin_amdgcn_s_barrier();
        __builtin_amdgcn_sched_barrier(0);

        // ---- phase 3: prefetch next-tile B-q0 (4) into BNEXT;
        //               stage B(t+2,q1); MFMA Q10 (av x BCUR)
        if (t_ + 1 < NT) {
            const short* lBn = &sB[(t_ + 1) & 1][0];
#pragma unroll
            for (int kc = 0; kc < 2; ++kc) {
                const int co = (((kc * 4 + quad) ^ rl7) << 3);
#pragma unroll
                for (int j = 0; j < 2; ++j)
                    BNEXT[j][kc] = *(const short8*)&lBn[(wn * 32 + j * 16 + lr) * 64 + co];
            }
        }
        if (t_ + 2 < NT) stageB(t_ + 2, 1);
        __builtin_amdgcn_s_setprio(1);
#pragma unroll
        for (int m = 0; m < 4; ++m)
#pragma unroll
            for (int j = 0; j < 2; ++j)
#pragma unroll
                for (int kc = 0; kc < 2; ++kc)
                    acc[4 + m][j] = __builtin_amdgcn_mfma_f32_16x16x32_bf16(
                        av[m][kc], BCUR[j][kc], acc[4 + m][j], 0, 0, 0);
        __builtin_amdgcn_s_setprio(0);
        __builtin_amdgcn_s_barrier();
        __builtin_amdgcn_sched_barrier(0);
    };

    // NT is even for all three GEMMs (K = 2048 -> NT = 32)
    for (int t = 0; t < NT; t += 2) {
        tile_body(t,     b0a, b0b);
        tile_body(t + 1, b0b, b0a);
    }

    // epilogue: row = bm*256 + wm*128 + mt*16 + quad*4 + r
    //           col = bn*256 + wn*64  + nt*16 + lr
    const int colbase = bn * 256 + wn * 64;
    const int rowbase = bm * 256 + wm * 128;

    if (EPILOGUE == 0) {
        __hip_bfloat16* O = (__hip_bfloat16*)Cout;
#pragma unroll
        for (int mt = 0; mt < 8; ++mt)
#pragma unroll
            for (int nt = 0; nt < 4; ++nt)
#pragma unroll
                for (int r = 0; r < 4; ++r) {
                    int row = rowbase + mt * 16 + quad * 4 + r;
                    int col = colbase + nt * 16 + lr;
                    O[(size_t)row * N + col] = __float2bfloat16(acc[mt][nt][r]);
                }
    } else if (EPILOGUE == 1) {
        __hip_bfloat16* O = (__hip_bfloat16*)Cout;
#pragma unroll
        for (int nt = 0; nt < 4; ++nt) {
            int col = colbase + nt * 16 + lr;
            int g = (col >> 9) & 3;   // uniform within a 16-col MFMA tile
            float bv = bias[col];
#pragma unroll
            for (int mt = 0; mt < 8; ++mt)
#pragma unroll
                for (int r = 0; r < 4; ++r) {
                    int row = rowbase + mt * 16 + quad * 4 + r;
                    float v = acc[mt][nt][r] + bv;
                    if (g == 0)       v = __expf(v);
                    else if (g == 3)  v = fast_tanh(v);
                    else              v = fast_sigmoid(v);
                    O[(size_t)row * N + col] = __float2bfloat16(v);
                }
        }
    } else {
        float* O = (float*)Cout;
#pragma unroll
        for (int mt = 0; mt < 8; ++mt)
#pragma unroll
            for (int nt = 0; nt < 4; ++nt)
#pragma unroll
                for (int r = 0; r < 4; ++r) {
                    int row = rowbase + mt * 16 + quad * 4 + r;
                    int col = colbase + nt * 16 + lr;
                    O[(size_t)row * N + col] = acc[mt][nt][r];
                }
    }
}

// ---------------------------------------------------------------------------
// Chunk-decomposed linear scan. c_t = f_t*c_{t-1} + i_t*cd_t is linear in c,
// so split SEQ into 16 chunks of 128:
//   pass1: per (dim, chunk) scan from c=0 in f32, keep P = prod(f) in f32;
//          store only chunk summaries cLast/PLast (f32, 1 MB).
//   pass2: per (dim, chunk) compose c_init from preceding summaries
//          in-register (<=15 f32 fmas, exact), re-scan the chunk re-reading
//          gates, store c (bf16) to cbuf.
// ---------------------------------------------------------------------------
struct G16 { unsigned short i[16], f[16], c[16]; };

__device__ __forceinline__ void load_g16(const unsigned short* __restrict__ g,
                                         int t0, G16& o)
{
#pragma unroll
    for (int j = 0; j < 16; ++j) {
        const unsigned short* gp = g + (size_t)(t0 + j) * G4;
        o.i[j] = gp[0]; o.f[j] = gp[512]; o.c[j] = gp[1536];
    }
}
__device__ __forceinline__ void comp_sum16(const G16& gg, float& c, float& P)
{
#pragma unroll
    for (int j = 0; j < 16; ++j) {
        float iv = b2f(gg.i[j]);
        float fv = b2f(gg.f[j]);
        float cd = b2f(gg.c[j]);
        c = fmaf(fv, c, iv * cd);
        P *= fv;
    }
}
__device__ __forceinline__ float comp_store16(const G16& gg, float c,
                                              __hip_bfloat16* __restrict__ cb, int t0)
{
#pragma unroll
    for (int j = 0; j < 16; ++j) {
        float iv = b2f(gg.i[j]);
        float fv = b2f(gg.f[j]);
        float cd = b2f(gg.c[j]);
        c = fmaf(fv, c, iv * cd);
        cb[(size_t)(t0 + j) * HIDDEN] = __float2bfloat16(c);
    }
    return c;
}

__global__ __launch_bounds__(256) void scan_pass1(
    const __hip_bfloat16* __restrict__ gates,
    float* __restrict__ cLast, float* __restrict__ PLast)
{
    int blk = blockIdx.x;              // 0..511
    int dh = blk & 1;
    int j  = (blk >> 1) & 15;
    int bh = blk >> 5;                 // 0..15
    int b = bh >> 2, h = bh & 3;
    int d = dh * 256 + threadIdx.x;    // 0..511
    int bhd = bh * 512 + d;

    const unsigned short* g = (const unsigned short*)gates
        + (size_t)(b * SEQ + j * CHUNK) * G4 + h * 2048 + d;

    float c = 0.0f, P = 1.0f;
    G16 A, B;
    load_g16(g, 0, A);
    for (int t0 = 0; t0 < CHUNK; t0 += 32) {
        load_g16(g, t0 + 16, B);
        comp_sum16(A, c, P);
        if (t0 + 32 < CHUNK) load_g16(g, t0 + 32, A);
        comp_sum16(B, c, P);
    }
    cLast[j * 8192 + bhd] = c;
    PLast[j * 8192 + bhd] = P;
}

__global__ __launch_bounds__(256) void scan_pass2(
    const __hip_bfloat16* __restrict__ gates,
    const float* __restrict__ cLast, const float* __restrict__ PLast,
    __hip_bfloat16* __restrict__ cbuf)
{
    int blk = blockIdx.x;              // 0..511
    int dh = blk & 1;
    int j  = (blk >> 1) & 15;
    int bh = blk >> 5;                 // 0..15
    int b = bh >> 2, h = bh & 3;
    int d = dh * 256 + threadIdx.x;    // 0..511
    int bhd = bh * 512 + d;

    // compose c_init for chunk j from preceding chunk summaries (exact f32)
    float c = 0.0f;
    for (int k = 0; k < j; ++k)
        c = fmaf(PLast[k * 8192 + bhd], c, cLast[k * 8192 + bhd]);

    const unsigned short* g = (const unsigned short*)gates
        + (size_t)(b * SEQ + j * CHUNK) * G4 + h * 2048 + d;
    __hip_bfloat16* cb = cbuf
        + (size_t)(b * SEQ + j * CHUNK) * HIDDEN + h * 512 + d;

    G16 A, B;
    load_g16(g, 0, A);
    for (int t0 = 0; t0 < CHUNK; t0 += 32) {
        load_g16(g, t0 + 16, B);
        c = comp_store16(A, c, cb, t0);
        if (t0 + 32 < CHUNK) load_g16(g, t0 + 32, A);
        c = comp_store16(B, c, cb, t0 + 16);
    }
}

// ---------------------------------------------------------------------------
// RMS-norm over HD=512 per (b,t,h), then h = o * tanh(c_norm). One wave per
// (b,t,h), 8 dims/lane, shuffle reduction. Writes h (bf16) IN-PLACE into the
// i-gate slot of gates (col h*2048 + d) for GEMM3's head-gather A staging.
// ---------------------------------------------------------------------------
__global__ __launch_bounds__(64) void norm_kernel(
    const __hip_bfloat16* __restrict__ cbuf, __hip_bfloat16* __restrict__ gates,
    const float* __restrict__ rms_w)
{
    int blk = blockIdx.x;                 // B*SEQ*H = 32768
    int h = blk & 3;
    int t = (blk >> 2) & (SEQ - 1);
    int b = blk >> 13;
    int lane = threadIdx.x;
    size_t tok = (size_t)(b * SEQ + t);

    BV8 cv; cv.u = *(const uint4*)(cbuf + tok * HIDDEN + h * 512 + lane * 8);
    float cf[8]; float s = 0.0f;
#pragma unroll
    for (int j = 0; j < 8; ++j) { cf[j] = b2f(cv.s[j]); s += cf[j] * cf[j]; }
#pragma unroll
    for (int off = 32; off > 0; off >>= 1) s += __shfl_xor(s, off, 64);
    float rs = rsqrtf(s * (1.0f / 512.0f) + EPSV);

    BV8 ov; ov.u = *(const uint4*)(gates + tok * G4 + h * 2048 + 1024 + lane * 8);
    float4 w0 = *(const float4*)&rms_w[lane * 8];
    float4 w1 = *(const float4*)&rms_w[lane * 8 + 4];
    float w[8] = { w0.x, w0.y, w0.z, w0.w, w1.x, w1.y, w1.z, w1.w };

    BV8 hv;
#pragma unroll
    for (int j = 0; j < 8; ++j) {
        float o = b2f(ov.s[j]);
        hv.h[j] = __float2bfloat16(o * fast_tanh(cf[j] * rs * w[j]));
    }
    *(uint4*)(gates + tok * G4 + h * 2048 + lane * 8) = hv.u;
}

// ---------------------------------------------------------------------------
// Workspace plan (192 MiB total, lifetime-aliased):
//  [0,  32MiB)  wgb (bf16 W_gate)   ... after GEMM2: [0,8M)=wob,
//                                       [8M,8.5M)=cLast, [8.5M,9M)=PLast
//  [32, 64MiB)  xpb (bf16 GEMM1 out)... after GEMM2: cbuf (bf16 c)
//  [64,192MiB)  gates (bf16)        ... before GEMM2: wib + xb
// ---------------------------------------------------------------------------
extern "C" void kernel_launch(void* const* d_in, const int* in_sizes, int n_in,
                              void* d_out, int out_size, void* d_ws, size_t ws_size,
                              hipStream_t stream)
{
    const float* x      = (const float*)d_in[0];   // (4,2048,2048)
    const float* W_in   = (const float*)d_in[1];   // (2048,2048)
    const float* W_gate = (const float*)d_in[2];   // (8192,2048)
    const float* b_gate = (const float*)d_in[3];   // (8192,)
    const float* rms_w  = (const float*)d_in[4];   // (512,)
    const float* W_out  = (const float*)d_in[5];   // (2048,2048)
    float* out = (float*)d_out;                    // (4,2048,2048)

    char* base = (char*)d_ws;
    __hip_bfloat16* wgb   = (__hip_bfloat16*)base;                             // 32 MiB
    __hip_bfloat16* xpb   = (__hip_bfloat16*)(base + (((size_t)32) << 20));    // 32 MiB
    __hip_bfloat16* gates = (__hip_bfloat16*)(base + (((size_t)64) << 20));    // 128 MiB
    // aliases (lifetime-disjoint, stream-ordered):
    __hip_bfloat16* wib  = gates;                                              // 8 MiB
    __hip_bfloat16* xb   = (__hip_bfloat16*)(base + (((size_t)72) << 20));     // 32 MiB
    __hip_bfloat16* wob  = wgb;                                                // 8 MiB
    float* cLast = (float*)(base + (((size_t)8) << 20));                       // 512 KiB
    float* PLast = (float*)(base + (((size_t)8) << 20) + (512 << 10));         // 512 KiB
    __hip_bfloat16* cbuf = xpb;                                                // 32 MiB

    // 1) casts to bf16 (wib/xb live in gates region; gates not written yet)
    cast_f32_bf16<<<(HIDDEN * DIMN) / 8 / 256, 256, 0, stream>>>(W_in, wib, (HIDDEN * DIMN) / 8);
    cast_f32_bf16<<<(NTOK * DIMN) / 8 / 256, 256, 0, stream>>>(x, xb, (NTOK * DIMN) / 8);
    cast_f32_bf16<<<(G4 * HIDDEN) / 8 / 256, 256, 0, stream>>>(W_gate, wgb, (G4 * HIDDEN) / 8);

    // 2) xp = x @ W_in^T  -> bf16
    {
        dim3 grid(HIDDEN / 256, NTOK / 256);   // 8 x 32 = 256 wgs
        gemm256<0, 0><<<grid, 512, 0, stream>>>(xb, wib, xpb, nullptr,
                                                NTOK, HIDDEN, DIMN, DIMN);
    }
    // 3) gates = act(xp @ W_gate^T + b) -> bf16 (overwrites wib/xb: dead now)
    {
        dim3 grid(G4 / 256, NTOK / 256);       // 32 x 32 = 1024 wgs
        gemm256<1, 0><<<grid, 512, 0, stream>>>(xpb, wgb, gates, b_gate,
                                                NTOK, G4, HIDDEN, HIDDEN);
    }
    // 4) cast W_out -> wob (overwrites wgb: dead now)
    cast_f32_bf16<<<(DIMN * HIDDEN) / 8 / 256, 256, 0, stream>>>(W_out, wob, (DIMN * HIDDEN) / 8);

    // 5) chunk-decomposed scan -> cbuf (bf16; overwrites xpb: dead now)
    scan_pass1<<<BATCH * NHEADS * NCHUNK * 2, 256, 0, stream>>>(gates, cLast, PLast);
    scan_pass2<<<BATCH * NHEADS * NCHUNK * 2, 256, 0, stream>>>(gates, cLast, PLast, cbuf);

    // 6) RMS-norm + output gate; h written into gates i-slot
    norm_kernel<<<BATCH * SEQ * NHEADS, 64, 0, stream>>>(cbuf, gates, rms_w);

    // 7) out = h @ W_out^T -> f32 (A head-gathered from gates i-slot)
    {
        dim3 grid(DIMN / 256, NTOK / 256);     // 8 x 32 = 256 wgs
        gemm256<2, 1><<<grid, 512, 0, stream>>>(gates, wob, out, nullptr,
                                                NTOK, DIMN, HIDDEN, G4);
    }
}

// Round 3
// 655.551 us; speedup vs baseline: 1.3137x; 1.3137x over previous
//
#include <hip/hip_runtime.h>
#include <hip/hip_bf16.h>
#include <stdint.h>

// Problem constants (fixed by reference)
#define DIMN    2048
#define HIDDEN  2048
#define NHEADS  4
#define HDIM    512
#define BATCH   4
#define SEQ     2048
#define NTOK    (BATCH*SEQ)      // 8192 tokens
#define G4      (4*HIDDEN)       // 8192 gate width
#define EPSV    1e-6f
#define CHUNK   128
#define NCHUNK  (SEQ/CHUNK)      // 16

typedef short short8 __attribute__((ext_vector_type(8)));
typedef float floatx4 __attribute__((ext_vector_type(4)));

union BV8 { uint4 u; __hip_bfloat16 h[8]; unsigned short s[8]; };

__device__ __forceinline__ float fast_sigmoid(float x) {
    return 1.0f / (1.0f + __expf(-x));
}
__device__ __forceinline__ float fast_tanh(float x) {
    return 1.0f - 2.0f / (__expf(2.0f * x) + 1.0f);
}
__device__ __forceinline__ float b2f(unsigned short u) {
    union { unsigned int ui; float f; } v; v.ui = ((unsigned int)u) << 16; return v.f;
}

// async global->LDS, 16B per lane; LDS dest = wave-uniform base + lane*16
__device__ __forceinline__ void gld_lds16(const void* gp, void* lp) {
    __builtin_amdgcn_global_load_lds(
        (const __attribute__((address_space(1))) void*)gp,
        (__attribute__((address_space(3))) void*)lp, 16, 0, 0);
}

// ---------------------------------------------------------------------------
// f32 -> bf16 cast, 8 elems/thread
// ---------------------------------------------------------------------------
__global__ __launch_bounds__(256) void cast_f32_bf16(
    const float* __restrict__ in, __hip_bfloat16* __restrict__ out, int n8)
{
    int i = blockIdx.x * 256 + threadIdx.x;
    if (i >= n8) return;
    const float4* p = (const float4*)(in + (size_t)i * 8);
    float4 a = p[0], b = p[1];
    BV8 v;
    v.h[0] = __float2bfloat16(a.x); v.h[1] = __float2bfloat16(a.y);
    v.h[2] = __float2bfloat16(a.z); v.h[3] = __float2bfloat16(a.w);
    v.h[4] = __float2bfloat16(b.x); v.h[5] = __float2bfloat16(b.y);
    v.h[6] = __float2bfloat16(b.z); v.h[7] = __float2bfloat16(b.w);
    *(uint4*)(out + (size_t)i * 8) = v.u;
}

// ---------------------------------------------------------------------------
// GEMM: C[M][N] = A[M][K] @ Bt[N][K]^T   (bf16 in, fp32 acc)
// 256x256 tile, BK=64, 512 threads = 8 waves (2M x 4N), each wave 128x64.
// Faithful m201 8-phase template (4 phases/K-tile), per phase:
//   { ds_reads; stage 1 chunk; [lgkmcnt(8) if 12 reads]; s_barrier;
//     asm lgkmcnt(0); setprio(1); 16 MFMA; setprio(0); s_barrier }
// NO sched_barrier(0) anywhere: register-only MFMAs may hoist above the
// inline lgkmcnt(0) and get compiler-counted lgkm waits against the C++
// ds_reads (the intended fine interleave). Round-1's sched_barrier(0) after
// the drain pinned all MFMAs below it = m141-style serialization (833 TF);
// round-2's barrier removal de-synced waves (680 TF). This is the proven
// structure (m201: 1563 TF @4k on this chip).
//
// Counted vmcnt: one vmcnt(6) per K-tile at phase-3 end (3 chunks = 6 loads
// in flight), vmcnt(0) once at t==NT-2, nothing at t==NT-1.
// Region-hazard ledger (every LDS overwrite >=2 barriers after the last
// read of that region; reads complete at their phase-end barrier since
// they are consumed by in-phase MFMA and lgkm completes in-order):
//   ph0 stage A(t+1,q1): region read as av in (t-1)ph2 -> done (t-1)ph2-end.
//   ph1 stage A(t+2,q0): region read as av in t ph0    -> done t ph0-end.
//   ph2 stage B(t+2,q0): region read as b0 in t ph0    -> done t ph0-end.
//   ph3 stage B(t+2,q1): region read as b1 in t ph1    -> done t ph1-end.
// Staging-visibility: vmcnt(6)+barrier at t ph3-end leaves only the newest
// 3 chunks {A(t+2,q0),B(t+2,q0),B(t+2,q1)} outstanding => all of tile t+1
// is resident before any t+1 read.
// Swizzle: source-chunk XOR (LDS[row][c]=G[row][c^(row&7)], 16B granules) --
// measured SQ_LDS_BANK_CONFLICT == 0 with the matching read-side XOR.
// EPILOGUE: 0 = bf16 store; 1 = bias+gate activations -> bf16; 2 = f32 store
// ASRC: 0 = contiguous rows; 1 = head-gather (row,k) -> Ag[row*lda +
//       (k>>9)*2048 + (k&511)]  (BK=64 chunk never crosses a 512 block)
// ---------------------------------------------------------------------------
template <int EPILOGUE, int ASRC>
__global__ __launch_bounds__(512, 2) void gemm256(
    const __hip_bfloat16* __restrict__ A,
    const __hip_bfloat16* __restrict__ Bt,
    void* __restrict__ Cout,
    const float* __restrict__ bias,
    int M, int N, int K, int lda)
{
    __shared__ __align__(16) short sA[2][256 * 64];   // 64 KiB
    __shared__ __align__(16) short sB[2][256 * 64];   // 64 KiB

    const int tid  = threadIdx.x;
    const int wave = tid >> 6, lane = tid & 63;
    const int wm = wave >> 2, wn = wave & 3;          // 2 x 4 wave grid
    const int quad = lane >> 4, lr = lane & 15;
    const int r8  = lane >> 3;                        // row within 8-row slab
    const int gcs = ((lane & 7) ^ r8) * 8;            // swizzled src chunk (shorts)
    const int rl7 = lr & 7;

    // bijective XCD swizzle (all launch shapes have nwg % 8 == 0)
    const int gx   = gridDim.x;
    const int nwg  = gx * gridDim.y;
    const int orig = blockIdx.y * gx + blockIdx.x;
    const int wg   = (orig & 7) * (nwg >> 3) + (orig >> 3);
    const int bm = wg / gx, bn = wg % gx;

    const short* Ag = (const short*)A + (size_t)(bm * 256) * lda;
    const short* Bg = (const short*)Bt + (size_t)(bn * 256) * K;

    floatx4 acc[8][4];
#pragma unroll
    for (int i = 0; i < 8; ++i)
#pragma unroll
        for (int j = 0; j < 4; ++j) acc[i][j] = (floatx4)0.0f;

    const int NT = K >> 6;

    auto stageA = [&](int kt, int qm) {
        const int kb = kt << 6;
        size_t acol;
        if (ASRC == 0) acol = (size_t)(kb + gcs);
        else           acol = (size_t)(((kb >> 9) << 11) + (kb & 511) + gcs);
        short* dst = &sA[kt & 1][0];
#pragma unroll
        for (int e = 0; e < 2; ++e) {
            const int base = qm * 128 + e * 64 + wave * 8;   // wave-uniform
            const int row  = base + r8;
            const int grow = ((row >> 6) & 1) * 128 + qm * 64 + (row & 63);
            gld_lds16(Ag + (size_t)grow * lda + acol, dst + base * 64);
        }
    };
    auto stageB = [&](int kt, int qn) {
        const int kb = kt << 6;
        short* dst = &sB[kt & 1][0];
#pragma unroll
        for (int e = 0; e < 2; ++e) {
            const int base = qn * 128 + e * 64 + wave * 8;   // wave-uniform
            const int row  = base + r8;
            const int grow = ((row >> 5) & 3) * 64 + qn * 32 + (row & 31);
            gld_lds16(Bg + (size_t)grow * K + kb + gcs, dst + base * 64);
        }
    };

    // prologue: tile0 c0..c3, tile1 {A-q0, B-q0, B-q1} (7 chunks, 14 loads);
    // vmcnt(6) -> tile0 fully resident (newest 3 chunks may be in flight).
    stageA(0, 0); stageB(0, 0); stageB(0, 1); stageA(0, 1);
    stageA(1, 0); stageB(1, 0); stageB(1, 1);
    asm volatile("s_waitcnt vmcnt(6)" ::: "memory");
    __builtin_amdgcn_s_barrier();

    short8 av[4][2], b0[2][2], b1[2][2];

    for (int t = 0; t < NT; ++t) {
        const short* lA = &sA[t & 1][0];
        const short* lB = &sB[t & 1][0];

        // ---- phase 0: read A-q0 (8) + B-q0 (4); stage A(t+1,q1); MFMA Q00
#pragma unroll
        for (int kc = 0; kc < 2; ++kc) {
            const int co = (((kc * 4 + quad) ^ rl7) << 3);
#pragma unroll
            for (int m = 0; m < 4; ++m)
                av[m][kc] = *(const short8*)&lA[(wm * 64 + m * 16 + lr) * 64 + co];
#pragma unroll
            for (int j = 0; j < 2; ++j)
                b0[j][kc] = *(const short8*)&lB[(wn * 32 + j * 16 + lr) * 64 + co];
        }
        if (t + 1 < NT) stageA(t + 1, 1);
        asm volatile("s_waitcnt lgkmcnt(8)" ::: "memory");
        __builtin_amdgcn_s_barrier();
        asm volatile("s_waitcnt lgkmcnt(0)" ::: "memory");
        __builtin_amdgcn_s_setprio(1);
#pragma unroll
        for (int m = 0; m < 4; ++m)
#pragma unroll
            for (int j = 0; j < 2; ++j)
#pragma unroll
                for (int kc = 0; kc < 2; ++kc)
                    acc[m][j] = __builtin_amdgcn_mfma_f32_16x16x32_bf16(
                        av[m][kc], b0[j][kc], acc[m][j], 0, 0, 0);
        __builtin_amdgcn_s_setprio(0);
        __builtin_amdgcn_s_barrier();

        // ---- phase 1: read B-q1 (4); stage A(t+2,q0); MFMA Q01
#pragma unroll
        for (int kc = 0; kc < 2; ++kc) {
            const int co = (((kc * 4 + quad) ^ rl7) << 3);
#pragma unroll
            for (int j = 0; j < 2; ++j)
                b1[j][kc] = *(const short8*)&lB[(128 + wn * 32 + j * 16 + lr) * 64 + co];
        }
        if (t + 2 < NT) stageA(t + 2, 0);
        __builtin_amdgcn_s_barrier();
        asm volatile("s_waitcnt lgkmcnt(0)" ::: "memory");
        __builtin_amdgcn_s_setprio(1);
#pragma unroll
        for (int m = 0; m < 4; ++m)
#pragma unroll
            for (int j = 0; j < 2; ++j)
#pragma unroll
                for (int kc = 0; kc < 2; ++kc)
                    acc[m][2 + j] = __builtin_amdgcn_mfma_f32_16x16x32_bf16(
                        av[m][kc], b1[j][kc], acc[m][2 + j], 0, 0, 0);
        __builtin_amdgcn_s_setprio(0);
        __builtin_amdgcn_s_barrier();

        // ---- phase 2: read A-q1 (8, overwrite av); stage B(t+2,q0); MFMA Q11
#pragma unroll
        for (int kc = 0; kc < 2; ++kc) {
            const int co = (((kc * 4 + quad) ^ rl7) << 3);
#pragma unroll
            for (int m = 0; m < 4; ++m)
                av[m][kc] = *(const short8*)&lA[(128 + wm * 64 + m * 16 + lr) * 64 + co];
        }
        if (t + 2 < NT) stageB(t + 2, 0);
        __builtin_amdgcn_s_barrier();
        asm volatile("s_waitcnt lgkmcnt(0)" ::: "memory");
        __builtin_amdgcn_s_setprio(1);
#pragma unroll
        for (int m = 0; m < 4; ++m)
#pragma unroll
            for (int j = 0; j < 2; ++j)
#pragma unroll
                for (int kc = 0; kc < 2; ++kc)
                    acc[4 + m][2 + j] = __builtin_amdgcn_mfma_f32_16x16x32_bf16(
                        av[m][kc], b1[j][kc], acc[4 + m][2 + j], 0, 0, 0);
        __builtin_amdgcn_s_setprio(0);
        __builtin_amdgcn_s_barrier();

        // ---- phase 3: regs only; stage B(t+2,q1); MFMA Q10; counted vmcnt
        if (t + 2 < NT) stageB(t + 2, 1);
        __builtin_amdgcn_s_barrier();
        __builtin_amdgcn_s_setprio(1);
#pragma unroll
        for (int m = 0; m < 4; ++m)
#pragma unroll
            for (int j = 0; j < 2; ++j)
#pragma unroll
                for (int kc = 0; kc < 2; ++kc)
                    acc[4 + m][j] = __builtin_amdgcn_mfma_f32_16x16x32_bf16(
                        av[m][kc], b0[j][kc], acc[4 + m][j], 0, 0, 0);
        __builtin_amdgcn_s_setprio(0);
        if (t < NT - 2)       asm volatile("s_waitcnt vmcnt(6)" ::: "memory");
        else if (t == NT - 2) asm volatile("s_waitcnt vmcnt(0)" ::: "memory");
        __builtin_amdgcn_s_barrier();
    }

    // epilogue: row = bm*256 + wm*128 + mt*16 + quad*4 + r
    //           col = bn*256 + wn*64  + nt*16 + lr
    const int colbase = bn * 256 + wn * 64;
    const int rowbase = bm * 256 + wm * 128;

    if (EPILOGUE == 0) {
        __hip_bfloat16* O = (__hip_bfloat16*)Cout;
#pragma unroll
        for (int mt = 0; mt < 8; ++mt)
#pragma unroll
            for (int nt = 0; nt < 4; ++nt)
#pragma unroll
                for (int r = 0; r < 4; ++r) {
                    int row = rowbase + mt * 16 + quad * 4 + r;
                    int col = colbase + nt * 16 + lr;
                    O[(size_t)row * N + col] = __float2bfloat16(acc[mt][nt][r]);
                }
    } else if (EPILOGUE == 1) {
        __hip_bfloat16* O = (__hip_bfloat16*)Cout;
#pragma unroll
        for (int nt = 0; nt < 4; ++nt) {
            int col = colbase + nt * 16 + lr;
            int g = (col >> 9) & 3;   // uniform within a 16-col MFMA tile
            float bv = bias[col];
#pragma unroll
            for (int mt = 0; mt < 8; ++mt)
#pragma unroll
                for (int r = 0; r < 4; ++r) {
                    int row = rowbase + mt * 16 + quad * 4 + r;
                    float v = acc[mt][nt][r] + bv;
                    if (g == 0)       v = __expf(v);
                    else if (g == 3)  v = fast_tanh(v);
                    else              v = fast_sigmoid(v);
                    O[(size_t)row * N + col] = __float2bfloat16(v);
                }
        }
    } else {
        float* O = (float*)Cout;
#pragma unroll
        for (int mt = 0; mt < 8; ++mt)
#pragma unroll
            for (int nt = 0; nt < 4; ++nt)
#pragma unroll
                for (int r = 0; r < 4; ++r) {
                    int row = rowbase + mt * 16 + quad * 4 + r;
                    int col = colbase + nt * 16 + lr;
                    O[(size_t)row * N + col] = acc[mt][nt][r];
                }
    }
}

// ---------------------------------------------------------------------------
// Chunk-decomposed linear scan. c_t = f_t*c_{t-1} + i_t*cd_t is linear in c,
// so split SEQ into 16 chunks of 128:
//   pass1: per (dim, chunk) scan from c=0 in f32, keep P = prod(f) in f32;
//          store only chunk summaries cLast/PLast (f32, 1 MB).
//   pass2: per (dim, chunk) compose c_init from preceding summaries
//          in-register (<=15 f32 fmas, exact), re-scan the chunk re-reading
//          gates, store c (bf16) to cbuf.
// ---------------------------------------------------------------------------
struct G16 { unsigned short i[16], f[16], c[16]; };

__device__ __forceinline__ void load_g16(const unsigned short* __restrict__ g,
                                         int t0, G16& o)
{
#pragma unroll
    for (int j = 0; j < 16; ++j) {
        const unsigned short* gp = g + (size_t)(t0 + j) * G4;
        o.i[j] = gp[0]; o.f[j] = gp[512]; o.c[j] = gp[1536];
    }
}
__device__ __forceinline__ void comp_sum16(const G16& gg, float& c, float& P)
{
#pragma unroll
    for (int j = 0; j < 16; ++j) {
        float iv = b2f(gg.i[j]);
        float fv = b2f(gg.f[j]);
        float cd = b2f(gg.c[j]);
        c = fmaf(fv, c, iv * cd);
        P *= fv;
    }
}
__device__ __forceinline__ float comp_store16(const G16& gg, float c,
                                              __hip_bfloat16* __restrict__ cb, int t0)
{
#pragma unroll
    for (int j = 0; j < 16; ++j) {
        float iv = b2f(gg.i[j]);
        float fv = b2f(gg.f[j]);
        float cd = b2f(gg.c[j]);
        c = fmaf(fv, c, iv * cd);
        cb[(size_t)(t0 + j) * HIDDEN] = __float2bfloat16(c);
    }
    return c;
}

__global__ __launch_bounds__(256) void scan_pass1(
    const __hip_bfloat16* __restrict__ gates,
    float* __restrict__ cLast, float* __restrict__ PLast)
{
    int blk = blockIdx.x;              // 0..511
    int dh = blk & 1;
    int j  = (blk >> 1) & 15;
    int bh = blk >> 5;                 // 0..15
    int b = bh >> 2, h = bh & 3;
    int d = dh * 256 + threadIdx.x;    // 0..511
    int bhd = bh * 512 + d;

    const unsigned short* g = (const unsigned short*)gates
        + (size_t)(b * SEQ + j * CHUNK) * G4 + h * 2048 + d;

    float c = 0.0f, P = 1.0f;
    G16 A, B;
    load_g16(g, 0, A);
    for (int t0 = 0; t0 < CHUNK; t0 += 32) {
        load_g16(g, t0 + 16, B);
        comp_sum16(A, c, P);
        if (t0 + 32 < CHUNK) load_g16(g, t0 + 32, A);
        comp_sum16(B, c, P);
    }
    cLast[j * 8192 + bhd] = c;
    PLast[j * 8192 + bhd] = P;
}

__global__ __launch_bounds__(256) void scan_pass2(
    const __hip_bfloat16* __restrict__ gates,
    const float* __restrict__ cLast, const float* __restrict__ PLast,
    __hip_bfloat16* __restrict__ cbuf)
{
    int blk = blockIdx.x;              // 0..511
    int dh = blk & 1;
    int j  = (blk >> 1) & 15;
    int bh = blk >> 5;                 // 0..15
    int b = bh >> 2, h = bh & 3;
    int d = dh * 256 + threadIdx.x;    // 0..511
    int bhd = bh * 512 + d;

    // compose c_init for chunk j from preceding chunk summaries (exact f32)
    float c = 0.0f;
    for (int k = 0; k < j; ++k)
        c = fmaf(PLast[k * 8192 + bhd], c, cLast[k * 8192 + bhd]);

    const unsigned short* g = (const unsigned short*)gates
        + (size_t)(b * SEQ + j * CHUNK) * G4 + h * 2048 + d;
    __hip_bfloat16* cb = cbuf
        + (size_t)(b * SEQ + j * CHUNK) * HIDDEN + h * 512 + d;

    G16 A, B;
    load_g16(g, 0, A);
    for (int t0 = 0; t0 < CHUNK; t0 += 32) {
        load_g16(g, t0 + 16, B);
        c = comp_store16(A, c, cb, t0);
        if (t0 + 32 < CHUNK) load_g16(g, t0 + 32, A);
        c = comp_store16(B, c, cb, t0 + 16);
    }
}

// ---------------------------------------------------------------------------
// RMS-norm over HD=512 per (b,t,h), then h = o * tanh(c_norm). One wave per
// (b,t,h), 8 dims/lane, shuffle reduction. Writes h (bf16) IN-PLACE into the
// i-gate slot of gates (col h*2048 + d) for GEMM3's head-gather A staging.
// ---------------------------------------------------------------------------
__global__ __launch_bounds__(64) void norm_kernel(
    const __hip_bfloat16* __restrict__ cbuf, __hip_bfloat16* __restrict__ gates,
    const float* __restrict__ rms_w)
{
    int blk = blockIdx.x;                 // B*SEQ*H = 32768
    int h = blk & 3;
    int t = (blk >> 2) & (SEQ - 1);
    int b = blk >> 13;
    int lane = threadIdx.x;
    size_t tok = (size_t)(b * SEQ + t);

    BV8 cv; cv.u = *(const uint4*)(cbuf + tok * HIDDEN + h * 512 + lane * 8);
    float cf[8]; float s = 0.0f;
#pragma unroll
    for (int j = 0; j < 8; ++j) { cf[j] = b2f(cv.s[j]); s += cf[j] * cf[j]; }
#pragma unroll
    for (int off = 32; off > 0; off >>= 1) s += __shfl_xor(s, off, 64);
    float rs = rsqrtf(s * (1.0f / 512.0f) + EPSV);

    BV8 ov; ov.u = *(const uint4*)(gates + tok * G4 + h * 2048 + 1024 + lane * 8);
    float4 w0 = *(const float4*)&rms_w[lane * 8];
    float4 w1 = *(const float4*)&rms_w[lane * 8 + 4];
    float w[8] = { w0.x, w0.y, w0.z, w0.w, w1.x, w1.y, w1.z, w1.w };

    BV8 hv;
#pragma unroll
    for (int j = 0; j < 8; ++j) {
        float o = b2f(ov.s[j]);
        hv.h[j] = __float2bfloat16(o * fast_tanh(cf[j] * rs * w[j]));
    }
    *(uint4*)(gates + tok * G4 + h * 2048 + lane * 8) = hv.u;
}

// ---------------------------------------------------------------------------
// Workspace plan (192 MiB total, lifetime-aliased):
//  [0,  32MiB)  wgb (bf16 W_gate)   ... after GEMM2: [0,8M)=wob,
//                                       [8M,8.5M)=cLast, [8.5M,9M)=PLast
//  [32, 64MiB)  xpb (bf16 GEMM1 out)... after GEMM2: cbuf (bf16 c)
//  [64,192MiB)  gates (bf16)        ... before GEMM2: wib + xb
// ---------------------------------------------------------------------------
extern "C" void kernel_launch(void* const* d_in, const int* in_sizes, int n_in,
                              void* d_out, int out_size, void* d_ws, size_t ws_size,
                              hipStream_t stream)
{
    const float* x      = (const float*)d_in[0];   // (4,2048,2048)
    const float* W_in   = (const float*)d_in[1];   // (2048,2048)
    const float* W_gate = (const float*)d_in[2];   // (8192,2048)
    const float* b_gate = (const float*)d_in[3];   // (8192,)
    const float* rms_w  = (const float*)d_in[4];   // (512,)
    const float* W_out  = (const float*)d_in[5];   // (2048,2048)
    float* out = (float*)d_out;                    // (4,2048,2048)

    char* base = (char*)d_ws;
    __hip_bfloat16* wgb   = (__hip_bfloat16*)base;                             // 32 MiB
    __hip_bfloat16* xpb   = (__hip_bfloat16*)(base + (((size_t)32) << 20));    // 32 MiB
    __hip_bfloat16* gates = (__hip_bfloat16*)(base + (((size_t)64) << 20));    // 128 MiB
    // aliases (lifetime-disjoint, stream-ordered):
    __hip_bfloat16* wib  = gates;                                              // 8 MiB
    __hip_bfloat16* xb   = (__hip_bfloat16*)(base + (((size_t)72) << 20));     // 32 MiB
    __hip_bfloat16* wob  = wgb;                                                // 8 MiB
    float* cLast = (float*)(base + (((size_t)8) << 20));                       // 512 KiB
    float* PLast = (float*)(base + (((size_t)8) << 20) + (512 << 10));         // 512 KiB
    __hip_bfloat16* cbuf = xpb;                                                // 32 MiB

    // 1) casts to bf16 (wib/xb live in gates region; gates not written yet)
    cast_f32_bf16<<<(HIDDEN * DIMN) / 8 / 256, 256, 0, stream>>>(W_in, wib, (HIDDEN * DIMN) / 8);
    cast_f32_bf16<<<(NTOK * DIMN) / 8 / 256, 256, 0, stream>>>(x, xb, (NTOK * DIMN) / 8);
    cast_f32_bf16<<<(G4 * HIDDEN) / 8 / 256, 256, 0, stream>>>(W_gate, wgb, (G4 * HIDDEN) / 8);

    // 2) xp = x @ W_in^T  -> bf16
    {
        dim3 grid(HIDDEN / 256, NTOK / 256);   // 8 x 32 = 256 wgs
        gemm256<0, 0><<<grid, 512, 0, stream>>>(xb, wib, xpb, nullptr,
                                                NTOK, HIDDEN, DIMN, DIMN);
    }
    // 3) gates = act(xp @ W_gate^T + b) -> bf16 (overwrites wib/xb: dead now)
    {
        dim3 grid(G4 / 256, NTOK / 256);       // 32 x 32 = 1024 wgs
        gemm256<1, 0><<<grid, 512, 0, stream>>>(xpb, wgb, gates, b_gate,
                                                NTOK, G4, HIDDEN, HIDDEN);
    }
    // 4) cast W_out -> wob (overwrites wgb: dead now)
    cast_f32_bf16<<<(DIMN * HIDDEN) / 8 / 256, 256, 0, stream>>>(W_out, wob, (DIMN * HIDDEN) / 8);

    // 5) chunk-decomposed scan -> cbuf (bf16; overwrites xpb: dead now)
    scan_pass1<<<BATCH * NHEADS * NCHUNK * 2, 256, 0, stream>>>(gates, cLast, PLast);
    scan_pass2<<<BATCH * NHEADS * NCHUNK * 2, 256, 0, stream>>>(gates, cLast, PLast, cbuf);

    // 6) RMS-norm + output gate; h written into gates i-slot
    norm_kernel<<<BATCH * SEQ * NHEADS, 64, 0, stream>>>(cbuf, gates, rms_w);

    // 7) out = h @ W_out^T -> f32 (A head-gathered from gates i-slot)
    {
        dim3 grid(DIMN / 256, NTOK / 256);     // 8 x 32 = 256 wgs
        gemm256<2, 1><<<grid, 512, 0, stream>>>(gates, wob, out, nullptr,
                                                NTOK, DIMN, HIDDEN, G4);
    }
}

// Round 4
// 632.857 us; speedup vs baseline: 1.3608x; 1.0359x over previous
//
#include <hip/hip_runtime.h>
#include <hip/hip_bf16.h>
#include <stdint.h>

// Problem constants (fixed by reference)
#define DIMN    2048
#define HIDDEN  2048
#define NHEADS  4
#define HDIM    512
#define BATCH   4
#define SEQ     2048
#define NTOK    (BATCH*SEQ)      // 8192 tokens
#define G4      (4*HIDDEN)       // 8192 gate width
#define EPSV    1e-6f
#define CHUNK   128
#define NCHUNK  (SEQ/CHUNK)      // 16

typedef short short8 __attribute__((ext_vector_type(8)));
typedef float floatx4 __attribute__((ext_vector_type(4)));

union BV8 { uint4 u; __hip_bfloat16 h[8]; unsigned short s[8]; };

__device__ __forceinline__ float fast_sigmoid(float x) {
    return 1.0f / (1.0f + __expf(-x));
}
__device__ __forceinline__ float fast_tanh(float x) {
    return 1.0f - 2.0f / (__expf(2.0f * x) + 1.0f);
}
__device__ __forceinline__ float b2f(unsigned short u) {
    union { unsigned int ui; float f; } v; v.ui = ((unsigned int)u) << 16; return v.f;
}

// async global->LDS, 16B per lane; LDS dest = wave-uniform base + lane*16
__device__ __forceinline__ void gld_lds16(const void* gp, void* lp) {
    __builtin_amdgcn_global_load_lds(
        (const __attribute__((address_space(1))) void*)gp,
        (__attribute__((address_space(3))) void*)lp, 16, 0, 0);
}

// ---------------------------------------------------------------------------
// f32 -> bf16 cast, 8 elems/thread
// ---------------------------------------------------------------------------
__global__ __launch_bounds__(256) void cast_f32_bf16(
    const float* __restrict__ in, __hip_bfloat16* __restrict__ out, int n8)
{
    int i = blockIdx.x * 256 + threadIdx.x;
    if (i >= n8) return;
    const float4* p = (const float4*)(in + (size_t)i * 8);
    float4 a = p[0], b = p[1];
    BV8 v;
    v.h[0] = __float2bfloat16(a.x); v.h[1] = __float2bfloat16(a.y);
    v.h[2] = __float2bfloat16(a.z); v.h[3] = __float2bfloat16(a.w);
    v.h[4] = __float2bfloat16(b.x); v.h[5] = __float2bfloat16(b.y);
    v.h[6] = __float2bfloat16(b.z); v.h[7] = __float2bfloat16(b.w);
    *(uint4*)(out + (size_t)i * 8) = v.u;
}

// ---------------------------------------------------------------------------
// GEMM: C[M][N] = A[M][K] @ Bt[N][K]^T   (bf16 in, fp32 acc)
// 256x256 tile, BK=64, 512 threads = 8 waves (2M x 4N), each wave 128x64.
// 4 phases/K-tile, ONE raw s_barrier per phase, NO manual lgkm waits:
//   { ds_reads; stage 1 chunk; setprio(1); 16 MFMA; setprio(0); s_barrier }
// The backend emits counted lgkmcnt(N) waits INSIDE the MFMA cluster (m97
// asm evidence: lgkmcnt(4/3/1/0) between ds_read and consuming MFMA), so
// MFMAs with early-ready operands issue while later reads are serviced ->
// per-phase cost ~ max(LDS, MFMA) instead of LDS + MFMA. Round-1/3's
// explicit per-phase lgkmcnt(0) drain forced the serial sum (measured
// 6200 cyc/K-tile = 2300 LDS + 2480 MFMA + overhead, MfmaUtil 36%).
//
// Safety WITHOUT the mid-phase drain:
//  - every ds_read in a phase is consumed by an MFMA in the SAME phase, so
//    all of a wave's reads are complete (register scoreboard) before it
//    reaches the phase-end barrier -> at any barrier, no read of the
//    current buffers is outstanding.
//  - region-hazard ledger (stage S writes region R; last read of R completed
//    >=1 barrier before S issues):
//      ph0 stage A(t+1,q1): R last read as av' in (t-1)ph2 -> (t-1)ph2-end.
//      ph1 stage A(t+2,q0): R last read as av  in t ph0    -> t ph0-end.
//      ph2 stage B(t+2,q0): R last read as b0  in t ph0    -> t ph0-end.
//      ph3 stage B(t+2,q1): R last read as b1  in t ph1    -> t ph1-end.
//  - staging visibility: vmcnt(6) at t ph3-end leaves only the newest 3
//    chunks {A(t+2,q0), B(t+2,q0), B(t+2,q1)} outstanding -> all of tile
//    t+1 resident before (t+1)ph0 reads. vmcnt(0) once at t==NT-2.
//  - reads precede stages in program order within each phase, so any
//    conservative compiler-inserted vmem-vs-LDS wait covers only chunks
//    staged >=1 phase earlier (round-2's same-phase read-after-stage is
//    avoided; ph3 has zero ds_reads).
// Swizzle: source-chunk XOR (LDS[row][c]=G[row][c^(row&7)], 16B granules) --
// measured SQ_LDS_BANK_CONFLICT == 0 with the matching read-side XOR.
// EPILOGUE: 0 = bf16 store; 1 = bias+gate activations -> bf16; 2 = f32 store
// ASRC: 0 = contiguous rows; 1 = head-gather (row,k) -> Ag[row*lda +
//       (k>>9)*2048 + (k&511)]  (BK=64 chunk never crosses a 512 block)
// ---------------------------------------------------------------------------
template <int EPILOGUE, int ASRC>
__global__ __launch_bounds__(512, 2) void gemm256(
    const __hip_bfloat16* __restrict__ A,
    const __hip_bfloat16* __restrict__ Bt,
    void* __restrict__ Cout,
    const float* __restrict__ bias,
    int M, int N, int K, int lda)
{
    __shared__ __align__(16) short sA[2][256 * 64];   // 64 KiB
    __shared__ __align__(16) short sB[2][256 * 64];   // 64 KiB

    const int tid  = threadIdx.x;
    const int wave = tid >> 6, lane = tid & 63;
    const int wm = wave >> 2, wn = wave & 3;          // 2 x 4 wave grid
    const int quad = lane >> 4, lr = lane & 15;
    const int r8  = lane >> 3;                        // row within 8-row slab
    const int gcs = ((lane & 7) ^ r8) * 8;            // swizzled src chunk (shorts)
    const int rl7 = lr & 7;

    // bijective XCD swizzle (all launch shapes have nwg % 8 == 0)
    const int gx   = gridDim.x;
    const int nwg  = gx * gridDim.y;
    const int orig = blockIdx.y * gx + blockIdx.x;
    const int wg   = (orig & 7) * (nwg >> 3) + (orig >> 3);
    const int bm = wg / gx, bn = wg % gx;

    const short* Ag = (const short*)A + (size_t)(bm * 256) * lda;
    const short* Bg = (const short*)Bt + (size_t)(bn * 256) * K;

    floatx4 acc[8][4];
#pragma unroll
    for (int i = 0; i < 8; ++i)
#pragma unroll
        for (int j = 0; j < 4; ++j) acc[i][j] = (floatx4)0.0f;

    const int NT = K >> 6;

    auto stageA = [&](int kt, int qm) {
        const int kb = kt << 6;
        size_t acol;
        if (ASRC == 0) acol = (size_t)(kb + gcs);
        else           acol = (size_t)(((kb >> 9) << 11) + (kb & 511) + gcs);
        short* dst = &sA[kt & 1][0];
#pragma unroll
        for (int e = 0; e < 2; ++e) {
            const int base = qm * 128 + e * 64 + wave * 8;   // wave-uniform
            const int row  = base + r8;
            const int grow = ((row >> 6) & 1) * 128 + qm * 64 + (row & 63);
            gld_lds16(Ag + (size_t)grow * lda + acol, dst + base * 64);
        }
    };
    auto stageB = [&](int kt, int qn) {
        const int kb = kt << 6;
        short* dst = &sB[kt & 1][0];
#pragma unroll
        for (int e = 0; e < 2; ++e) {
            const int base = qn * 128 + e * 64 + wave * 8;   // wave-uniform
            const int row  = base + r8;
            const int grow = ((row >> 5) & 3) * 64 + qn * 32 + (row & 31);
            gld_lds16(Bg + (size_t)grow * K + kb + gcs, dst + base * 64);
        }
    };

    // prologue: tile0 c0..c3, tile1 {A-q0, B-q0, B-q1} (7 chunks, 14 loads);
    // vmcnt(6) -> tile0 fully resident (newest 3 chunks may be in flight).
    stageA(0, 0); stageB(0, 0); stageB(0, 1); stageA(0, 1);
    stageA(1, 0); stageB(1, 0); stageB(1, 1);
    asm volatile("s_waitcnt vmcnt(6)" ::: "memory");
    __builtin_amdgcn_s_barrier();

    short8 av[4][2], b0[2][2], b1[2][2];

    for (int t = 0; t < NT; ++t) {
        const short* lA = &sA[t & 1][0];
        const short* lB = &sB[t & 1][0];

        // ---- phase 0: read A-q0 (8) + B-q0 (4); stage A(t+1,q1); MFMA Q00
#pragma unroll
        for (int kc = 0; kc < 2; ++kc) {
            const int co = (((kc * 4 + quad) ^ rl7) << 3);
#pragma unroll
            for (int m = 0; m < 4; ++m)
                av[m][kc] = *(const short8*)&lA[(wm * 64 + m * 16 + lr) * 64 + co];
#pragma unroll
            for (int j = 0; j < 2; ++j)
                b0[j][kc] = *(const short8*)&lB[(wn * 32 + j * 16 + lr) * 64 + co];
        }
        if (t + 1 < NT) stageA(t + 1, 1);
        __builtin_amdgcn_s_setprio(1);
#pragma unroll
        for (int m = 0; m < 4; ++m)
#pragma unroll
            for (int j = 0; j < 2; ++j)
#pragma unroll
                for (int kc = 0; kc < 2; ++kc)
                    acc[m][j] = __builtin_amdgcn_mfma_f32_16x16x32_bf16(
                        av[m][kc], b0[j][kc], acc[m][j], 0, 0, 0);
        __builtin_amdgcn_s_setprio(0);
        __builtin_amdgcn_s_barrier();

        // ---- phase 1: read B-q1 (4); stage A(t+2,q0); MFMA Q01
#pragma unroll
        for (int kc = 0; kc < 2; ++kc) {
            const int co = (((kc * 4 + quad) ^ rl7) << 3);
#pragma unroll
            for (int j = 0; j < 2; ++j)
                b1[j][kc] = *(const short8*)&lB[(128 + wn * 32 + j * 16 + lr) * 64 + co];
        }
        if (t + 2 < NT) stageA(t + 2, 0);
        __builtin_amdgcn_s_setprio(1);
#pragma unroll
        for (int m = 0; m < 4; ++m)
#pragma unroll
            for (int j = 0; j < 2; ++j)
#pragma unroll
                for (int kc = 0; kc < 2; ++kc)
                    acc[m][2 + j] = __builtin_amdgcn_mfma_f32_16x16x32_bf16(
                        av[m][kc], b1[j][kc], acc[m][2 + j], 0, 0, 0);
        __builtin_amdgcn_s_setprio(0);
        __builtin_amdgcn_s_barrier();

        // ---- phase 2: read A-q1 (8, overwrite av); stage B(t+2,q0); MFMA Q11
#pragma unroll
        for (int kc = 0; kc < 2; ++kc) {
            const int co = (((kc * 4 + quad) ^ rl7) << 3);
#pragma unroll
            for (int m = 0; m < 4; ++m)
                av[m][kc] = *(const short8*)&lA[(128 + wm * 64 + m * 16 + lr) * 64 + co];
        }
        if (t + 2 < NT) stageB(t + 2, 0);
        __builtin_amdgcn_s_setprio(1);
#pragma unroll
        for (int m = 0; m < 4; ++m)
#pragma unroll
            for (int j = 0; j < 2; ++j)
#pragma unroll
                for (int kc = 0; kc < 2; ++kc)
                    acc[4 + m][2 + j] = __builtin_amdgcn_mfma_f32_16x16x32_bf16(
                        av[m][kc], b1[j][kc], acc[4 + m][2 + j], 0, 0, 0);
        __builtin_amdgcn_s_setprio(0);
        __builtin_amdgcn_s_barrier();

        // ---- phase 3: regs only; stage B(t+2,q1); MFMA Q10; counted vmcnt
        if (t + 2 < NT) stageB(t + 2, 1);
        __builtin_amdgcn_s_setprio(1);
#pragma unroll
        for (int m = 0; m < 4; ++m)
#pragma unroll
            for (int j = 0; j < 2; ++j)
#pragma unroll
                for (int kc = 0; kc < 2; ++kc)
                    acc[4 + m][j] = __builtin_amdgcn_mfma_f32_16x16x32_bf16(
                        av[m][kc], b0[j][kc], acc[4 + m][j], 0, 0, 0);
        __builtin_amdgcn_s_setprio(0);
        if (t < NT - 2)       asm volatile("s_waitcnt vmcnt(6)" ::: "memory");
        else if (t == NT - 2) asm volatile("s_waitcnt vmcnt(0)" ::: "memory");
        __builtin_amdgcn_s_barrier();
    }

    // epilogue: row = bm*256 + wm*128 + mt*16 + quad*4 + r
    //           col = bn*256 + wn*64  + nt*16 + lr
    const int colbase = bn * 256 + wn * 64;
    const int rowbase = bm * 256 + wm * 128;

    if (EPILOGUE == 0) {
        __hip_bfloat16* O = (__hip_bfloat16*)Cout;
#pragma unroll
        for (int mt = 0; mt < 8; ++mt)
#pragma unroll
            for (int nt = 0; nt < 4; ++nt)
#pragma unroll
                for (int r = 0; r < 4; ++r) {
                    int row = rowbase + mt * 16 + quad * 4 + r;
                    int col = colbase + nt * 16 + lr;
                    O[(size_t)row * N + col] = __float2bfloat16(acc[mt][nt][r]);
                }
    } else if (EPILOGUE == 1) {
        __hip_bfloat16* O = (__hip_bfloat16*)Cout;
#pragma unroll
        for (int nt = 0; nt < 4; ++nt) {
            int col = colbase + nt * 16 + lr;
            int g = (col >> 9) & 3;   // uniform within a 16-col MFMA tile
            float bv = bias[col];
#pragma unroll
            for (int mt = 0; mt < 8; ++mt)
#pragma unroll
                for (int r = 0; r < 4; ++r) {
                    int row = rowbase + mt * 16 + quad * 4 + r;
                    float v = acc[mt][nt][r] + bv;
                    if (g == 0)       v = __expf(v);
                    else if (g == 3)  v = fast_tanh(v);
                    else              v = fast_sigmoid(v);
                    O[(size_t)row * N + col] = __float2bfloat16(v);
                }
        }
    } else {
        float* O = (float*)Cout;
#pragma unroll
        for (int mt = 0; mt < 8; ++mt)
#pragma unroll
            for (int nt = 0; nt < 4; ++nt)
#pragma unroll
                for (int r = 0; r < 4; ++r) {
                    int row = rowbase + mt * 16 + quad * 4 + r;
                    int col = colbase + nt * 16 + lr;
                    O[(size_t)row * N + col] = acc[mt][nt][r];
                }
    }
}

// ---------------------------------------------------------------------------
// Chunk-decomposed linear scan. c_t = f_t*c_{t-1} + i_t*cd_t is linear in c,
// so split SEQ into 16 chunks of 128:
//   pass1: per (dim, chunk) scan from c=0 in f32, keep P = prod(f) in f32;
//          store only chunk summaries cLast/PLast (f32, 1 MB).
//   pass2: per (dim, chunk) compose c_init from preceding summaries
//          in-register (<=15 f32 fmas, exact), re-scan the chunk re-reading
//          gates, store c (bf16) to cbuf.
// ---------------------------------------------------------------------------
struct G16 { unsigned short i[16], f[16], c[16]; };

__device__ __forceinline__ void load_g16(const unsigned short* __restrict__ g,
                                         int t0, G16& o)
{
#pragma unroll
    for (int j = 0; j < 16; ++j) {
        const unsigned short* gp = g + (size_t)(t0 + j) * G4;
        o.i[j] = gp[0]; o.f[j] = gp[512]; o.c[j] = gp[1536];
    }
}
__device__ __forceinline__ void comp_sum16(const G16& gg, float& c, float& P)
{
#pragma unroll
    for (int j = 0; j < 16; ++j) {
        float iv = b2f(gg.i[j]);
        float fv = b2f(gg.f[j]);
        float cd = b2f(gg.c[j]);
        c = fmaf(fv, c, iv * cd);
        P *= fv;
    }
}
__device__ __forceinline__ float comp_store16(const G16& gg, float c,
                                              __hip_bfloat16* __restrict__ cb, int t0)
{
#pragma unroll
    for (int j = 0; j < 16; ++j) {
        float iv = b2f(gg.i[j]);
        float fv = b2f(gg.f[j]);
        float cd = b2f(gg.c[j]);
        c = fmaf(fv, c, iv * cd);
        cb[(size_t)(t0 + j) * HIDDEN] = __float2bfloat16(c);
    }
    return c;
}

__global__ __launch_bounds__(256) void scan_pass1(
    const __hip_bfloat16* __restrict__ gates,
    float* __restrict__ cLast, float* __restrict__ PLast)
{
    int blk = blockIdx.x;              // 0..511
    int dh = blk & 1;
    int j  = (blk >> 1) & 15;
    int bh = blk >> 5;                 // 0..15
    int b = bh >> 2, h = bh & 3;
    int d = dh * 256 + threadIdx.x;    // 0..511
    int bhd = bh * 512 + d;

    const unsigned short* g = (const unsigned short*)gates
        + (size_t)(b * SEQ + j * CHUNK) * G4 + h * 2048 + d;

    float c = 0.0f, P = 1.0f;
    G16 A, B;
    load_g16(g, 0, A);
    for (int t0 = 0; t0 < CHUNK; t0 += 32) {
        load_g16(g, t0 + 16, B);
        comp_sum16(A, c, P);
        if (t0 + 32 < CHUNK) load_g16(g, t0 + 32, A);
        comp_sum16(B, c, P);
    }
    cLast[j * 8192 + bhd] = c;
    PLast[j * 8192 + bhd] = P;
}

__global__ __launch_bounds__(256) void scan_pass2(
    const __hip_bfloat16* __restrict__ gates,
    const float* __restrict__ cLast, const float* __restrict__ PLast,
    __hip_bfloat16* __restrict__ cbuf)
{
    int blk = blockIdx.x;              // 0..511
    int dh = blk & 1;
    int j  = (blk >> 1) & 15;
    int bh = blk >> 5;                 // 0..15
    int b = bh >> 2, h = bh & 3;
    int d = dh * 256 + threadIdx.x;    // 0..511
    int bhd = bh * 512 + d;

    // compose c_init for chunk j from preceding chunk summaries (exact f32)
    float c = 0.0f;
    for (int k = 0; k < j; ++k)
        c = fmaf(PLast[k * 8192 + bhd], c, cLast[k * 8192 + bhd]);

    const unsigned short* g = (const unsigned short*)gates
        + (size_t)(b * SEQ + j * CHUNK) * G4 + h * 2048 + d;
    __hip_bfloat16* cb = cbuf
        + (size_t)(b * SEQ + j * CHUNK) * HIDDEN + h * 512 + d;

    G16 A, B;
    load_g16(g, 0, A);
    for (int t0 = 0; t0 < CHUNK; t0 += 32) {
        load_g16(g, t0 + 16, B);
        c = comp_store16(A, c, cb, t0);
        if (t0 + 32 < CHUNK) load_g16(g, t0 + 32, A);
        c = comp_store16(B, c, cb, t0 + 16);
    }
}

// ---------------------------------------------------------------------------
// RMS-norm over HD=512 per (b,t,h), then h = o * tanh(c_norm). One wave per
// (b,t,h), 8 dims/lane, shuffle reduction. Writes h (bf16) IN-PLACE into the
// i-gate slot of gates (col h*2048 + d) for GEMM3's head-gather A staging.
// ---------------------------------------------------------------------------
__global__ __launch_bounds__(64) void norm_kernel(
    const __hip_bfloat16* __restrict__ cbuf, __hip_bfloat16* __restrict__ gates,
    const float* __restrict__ rms_w)
{
    int blk = blockIdx.x;                 // B*SEQ*H = 32768
    int h = blk & 3;
    int t = (blk >> 2) & (SEQ - 1);
    int b = blk >> 13;
    int lane = threadIdx.x;
    size_t tok = (size_t)(b * SEQ + t);

    BV8 cv; cv.u = *(const uint4*)(cbuf + tok * HIDDEN + h * 512 + lane * 8);
    float cf[8]; float s = 0.0f;
#pragma unroll
    for (int j = 0; j < 8; ++j) { cf[j] = b2f(cv.s[j]); s += cf[j] * cf[j]; }
#pragma unroll
    for (int off = 32; off > 0; off >>= 1) s += __shfl_xor(s, off, 64);
    float rs = rsqrtf(s * (1.0f / 512.0f) + EPSV);

    BV8 ov; ov.u = *(const uint4*)(gates + tok * G4 + h * 2048 + 1024 + lane * 8);
    float4 w0 = *(const float4*)&rms_w[lane * 8];
    float4 w1 = *(const float4*)&rms_w[lane * 8 + 4];
    float w[8] = { w0.x, w0.y, w0.z, w0.w, w1.x, w1.y, w1.z, w1.w };

    BV8 hv;
#pragma unroll
    for (int j = 0; j < 8; ++j) {
        float o = b2f(ov.s[j]);
        hv.h[j] = __float2bfloat16(o * fast_tanh(cf[j] * rs * w[j]));
    }
    *(uint4*)(gates + tok * G4 + h * 2048 + lane * 8) = hv.u;
}

// ---------------------------------------------------------------------------
// Workspace plan (192 MiB total, lifetime-aliased):
//  [0,  32MiB)  wgb (bf16 W_gate)   ... after GEMM2: [0,8M)=wob,
//                                       [8M,8.5M)=cLast, [8.5M,9M)=PLast
//  [32, 64MiB)  xpb (bf16 GEMM1 out)... after GEMM2: cbuf (bf16 c)
//  [64,192MiB)  gates (bf16)        ... before GEMM2: wib + xb
// ---------------------------------------------------------------------------
extern "C" void kernel_launch(void* const* d_in, const int* in_sizes, int n_in,
                              void* d_out, int out_size, void* d_ws, size_t ws_size,
                              hipStream_t stream)
{
    const float* x      = (const float*)d_in[0];   // (4,2048,2048)
    const float* W_in   = (const float*)d_in[1];   // (2048,2048)
    const float* W_gate = (const float*)d_in[2];   // (8192,2048)
    const float* b_gate = (const float*)d_in[3];   // (8192,)
    const float* rms_w  = (const float*)d_in[4];   // (512,)
    const float* W_out  = (const float*)d_in[5];   // (2048,2048)
    float* out = (float*)d_out;                    // (4,2048,2048)

    char* base = (char*)d_ws;
    __hip_bfloat16* wgb   = (__hip_bfloat16*)base;                             // 32 MiB
    __hip_bfloat16* xpb   = (__hip_bfloat16*)(base + (((size_t)32) << 20));    // 32 MiB
    __hip_bfloat16* gates = (__hip_bfloat16*)(base + (((size_t)64) << 20));    // 128 MiB
    // aliases (lifetime-disjoint, stream-ordered):
    __hip_bfloat16* wib  = gates;                                              // 8 MiB
    __hip_bfloat16* xb   = (__hip_bfloat16*)(base + (((size_t)72) << 20));     // 32 MiB
    __hip_bfloat16* wob  = wgb;                                                // 8 MiB
    float* cLast = (float*)(base + (((size_t)8) << 20));                       // 512 KiB
    float* PLast = (float*)(base + (((size_t)8) << 20) + (512 << 10));         // 512 KiB
    __hip_bfloat16* cbuf = xpb;                                                // 32 MiB

    // 1) casts to bf16 (wib/xb live in gates region; gates not written yet)
    cast_f32_bf16<<<(HIDDEN * DIMN) / 8 / 256, 256, 0, stream>>>(W_in, wib, (HIDDEN * DIMN) / 8);
    cast_f32_bf16<<<(NTOK * DIMN) / 8 / 256, 256, 0, stream>>>(x, xb, (NTOK * DIMN) / 8);
    cast_f32_bf16<<<(G4 * HIDDEN) / 8 / 256, 256, 0, stream>>>(W_gate, wgb, (G4 * HIDDEN) / 8);

    // 2) xp = x @ W_in^T  -> bf16
    {
        dim3 grid(HIDDEN / 256, NTOK / 256);   // 8 x 32 = 256 wgs
        gemm256<0, 0><<<grid, 512, 0, stream>>>(xb, wib, xpb, nullptr,
                                                NTOK, HIDDEN, DIMN, DIMN);
    }
    // 3) gates = act(xp @ W_gate^T + b) -> bf16 (overwrites wib/xb: dead now)
    {
        dim3 grid(G4 / 256, NTOK / 256);       // 32 x 32 = 1024 wgs
        gemm256<1, 0><<<grid, 512, 0, stream>>>(xpb, wgb, gates, b_gate,
                                                NTOK, G4, HIDDEN, HIDDEN);
    }
    // 4) cast W_out -> wob (overwrites wgb: dead now)
    cast_f32_bf16<<<(DIMN * HIDDEN) / 8 / 256, 256, 0, stream>>>(W_out, wob, (DIMN * HIDDEN) / 8);

    // 5) chunk-decomposed scan -> cbuf (bf16; overwrites xpb: dead now)
    scan_pass1<<<BATCH * NHEADS * NCHUNK * 2, 256, 0, stream>>>(gates, cLast, PLast);
    scan_pass2<<<BATCH * NHEADS * NCHUNK * 2, 256, 0, stream>>>(gates, cLast, PLast, cbuf);

    // 6) RMS-norm + output gate; h written into gates i-slot
    norm_kernel<<<BATCH * SEQ * NHEADS, 64, 0, stream>>>(cbuf, gates, rms_w);

    // 7) out = h @ W_out^T -> f32 (A head-gathered from gates i-slot)
    {
        dim3 grid(DIMN / 256, NTOK / 256);     // 8 x 32 = 256 wgs
        gemm256<2, 1><<<grid, 512, 0, stream>>>(gates, wob, out, nullptr,
                                                NTOK, DIMN, HIDDEN, G4);
    }
}